// Round 1
// baseline (478.365 us; speedup 1.0000x reference)
//
#include <hip/hip_runtime.h>
#include <math.h>

#define TPB 576  // 9 waves of 64; one image per block

__device__ __forceinline__ float f4c(const float4 v, int p) {
    return (p == 0) ? v.x : ((p == 1) ? v.y : v.z);
}

__global__ __launch_bounds__(TPB) void fused_pipeline(
    const float* __restrict__ x,    // [N,784]
    const float* __restrict__ W1,   // [32,1,3,3]
    const float* __restrict__ b1,   // [32]
    const float* __restrict__ W2,   // [3,32,3,3]
    const float* __restrict__ b2,   // [3]
    const float* __restrict__ Wl,   // [10,384]
    const float* __restrict__ bl,   // [10]
    float* __restrict__ out)        // [N,10]
{
    __shared__ float  xs[784];
    __shared__ float4 buf[2][676];    // conv1 out, 4 channels packed, double-buffered
    __shared__ float4 s2v[26 * 26];   // conv2 out (3 patches in .x/.y/.z), zero border
    __shared__ float  hist[384];      // [patch][bin*16+cell]
    __shared__ float  nrm[3];
    __shared__ float  lg[10];

    const int n = blockIdx.x;
    const int t = threadIdx.x;

    // ---- stage inputs ----
    for (int i = t; i < 784; i += TPB) xs[i] = x[n * 784 + i];
    for (int i = t; i < 676; i += TPB) s2v[i] = make_float4(0.f, 0.f, 0.f, 0.f);
    if (t < 384) hist[t] = 0.f;
    __syncthreads();

    // conv1 pixel assignment: pixel0 = t (always), pixel1 = 576+t (t<100)
    const int p0i = t / 26, p0j = t % 26;
    float xn[9];
#pragma unroll
    for (int q = 0; q < 9; ++q)
        xn[q] = xs[(p0i + q / 3) * 28 + (p0j + q % 3)];
    const int p1  = 576 + t;
    const int p1i = p1 / 26, p1j = p1 % 26;

    // conv2 output pixel for this thread
    const int i2 = t / 24, j2 = t % 24;

    float acc[3] = {0.f, 0.f, 0.f};

#pragma unroll 1
    for (int cg = 0; cg < 8; ++cg) {
        const int c0 = cg * 4;
        // ---- conv1: channels c0..c0+3 -> buf[cg&1], ReLU ----
        {
            float4 v;
            float* vp = (float*)&v;
#pragma unroll
            for (int cc = 0; cc < 4; ++cc) {
                const float* w = W1 + (c0 + cc) * 9;  // wave-uniform -> s_load
                float s = b1[c0 + cc];
#pragma unroll
                for (int q = 0; q < 9; ++q) s += w[q] * xn[q];
                vp[cc] = fmaxf(s, 0.f);
            }
            buf[cg & 1][t] = v;
        }
        if (t < 100) {
            float4 v;
            float* vp = (float*)&v;
#pragma unroll
            for (int cc = 0; cc < 4; ++cc) {
                const float* w = W1 + (c0 + cc) * 9;
                float s = b1[c0 + cc];
#pragma unroll
                for (int q = 0; q < 9; ++q)
                    s += w[q] * xs[(p1i + q / 3) * 28 + (p1j + q % 3)];
                vp[cc] = fmaxf(s, 0.f);
            }
            buf[cg & 1][p1] = v;
        }
        __syncthreads();
        // ---- conv2: accumulate 4 channels x 9 taps x 3 outputs ----
        const float4* bp = buf[cg & 1];
#pragma unroll
        for (int di = 0; di < 3; ++di) {
            const float4 a0 = bp[(i2 + di) * 26 + j2 + 0];
            const float4 a1 = bp[(i2 + di) * 26 + j2 + 1];
            const float4 a2 = bp[(i2 + di) * 26 + j2 + 2];
#pragma unroll
            for (int k = 0; k < 3; ++k) {
                // W2 flat [k][c][r*3+s]; wave-uniform -> s_load
                const float* w = W2 + k * 288 + c0 * 9 + di * 3;
                acc[k] += w[0] * a0.x + w[9]  * a0.y + w[18] * a0.z + w[27] * a0.w
                        + w[1] * a1.x + w[10] * a1.y + w[19] * a1.z + w[28] * a1.w
                        + w[2] * a2.x + w[11] * a2.y + w[20] * a2.z + w[29] * a2.w;
            }
        }
        // no barrier needed here: double buffer + the barrier inside next iter
    }

    // conv2 bias; pack 3 patches into float4 lanes, interior of zero-padded 26x26
    s2v[(i2 + 1) * 26 + (j2 + 1)] =
        make_float4(acc[0] + b2[0], acc[1] + b2[1], acc[2] + b2[2], 0.f);
    __syncthreads();

    // ---- SIFT: Sobel -> 8-bin hard-argmax histogram (atomic, exact tie semantics) ----
    {
        const float C0 = 0.92387953f;  // cos(pi/8)
        const float C1 = 0.38268343f;  // cos(3pi/8)
        const int cell = (i2 / 6) * 4 + (j2 / 6);

        float4 Pr[3][3];
#pragma unroll
        for (int r = 0; r < 3; ++r)
#pragma unroll
            for (int c = 0; c < 3; ++c)
                Pr[r][c] = s2v[(i2 + r) * 26 + (j2 + c)];

#pragma unroll
        for (int p = 0; p < 3; ++p) {
            const float p00 = f4c(Pr[0][0], p), p01 = f4c(Pr[0][1], p), p02 = f4c(Pr[0][2], p);
            const float p10 = f4c(Pr[1][0], p),                         p12 = f4c(Pr[1][2], p);
            const float p20 = f4c(Pr[2][0], p), p21 = f4c(Pr[2][1], p), p22 = f4c(Pr[2][2], p);
            const float Ix = (p02 - p00) + 2.f * (p12 - p10) + (p22 - p20);
            const float Iy = (p20 - p00) + 2.f * (p21 - p01) + (p22 - p02);
            const float mag = sqrtf(Ix * Ix + Iy * Iy + 1e-12f);
            float cs[8];
            cs[0] =  C0 * Ix + C1 * Iy;
            cs[1] =  C1 * Ix + C0 * Iy;
            cs[2] = -C1 * Ix + C0 * Iy;
            cs[3] = -C0 * Ix + C1 * Iy;
            cs[4] = -C0 * Ix - C1 * Iy;
            cs[5] = -C1 * Ix - C0 * Iy;
            cs[6] =  C1 * Ix - C0 * Iy;
            cs[7] =  C0 * Ix - C1 * Iy;
            float cmax = cs[0];
#pragma unroll
            for (int k = 1; k < 8; ++k) cmax = fmaxf(cmax, cs[k]);
#pragma unroll
            for (int k = 0; k < 8; ++k)
                if (cs[k] == cmax)
                    atomicAdd(&hist[p * 128 + k * 16 + cell], mag);
        }
    }
    __syncthreads();

    // ---- per-patch L2 norm (one wave per patch) ----
    if (t < 192) {
        const int p = t >> 6, l = t & 63;
        const float v0 = hist[p * 128 + l], v1 = hist[p * 128 + l + 64];
        float s = v0 * v0 + v1 * v1;
#pragma unroll
        for (int off = 32; off; off >>= 1) s += __shfl_down(s, off);
        if (l == 0) nrm[p] = sqrtf(s) + 1e-8f;
    }
    __syncthreads();

    // ---- normalize + pow 0.9 (in place) ----
    if (t < 384) {
        const int p = t >> 7;
        const float v = hist[t] / nrm[p] + 1e-8f;
        hist[t] = powf(v, 0.9f);
    }
    __syncthreads();

    // ---- linear 384 -> 10 (16 lanes per output) ----
    if (t < 160) {
        const int o = t >> 4, l = t & 15;
        const float* w = Wl + o * 384;
        float s = 0.f;
#pragma unroll 4
        for (int q = l; q < 384; q += 16) s += hist[q] * w[q];
#pragma unroll
        for (int off = 8; off; off >>= 1) s += __shfl_down(s, off, 16);
        if (l == 0) lg[o] = s + bl[o];
    }
    __syncthreads();

    // ---- relu + softmax ----
    if (t == 0) {
        float z[10], m = 0.f, ssum = 0.f;
#pragma unroll
        for (int o = 0; o < 10; ++o) { z[o] = fmaxf(lg[o], 0.f); m = fmaxf(m, z[o]); }
#pragma unroll
        for (int o = 0; o < 10; ++o) { z[o] = expf(z[o] - m); ssum += z[o]; }
        const float inv = 1.f / ssum;
#pragma unroll
        for (int o = 0; o < 10; ++o) lg[o] = z[o] * inv;
    }
    __syncthreads();
    if (t < 10) out[n * 10 + t] = lg[t];
}

extern "C" void kernel_launch(void* const* d_in, const int* in_sizes, int n_in,
                              void* d_out, int out_size, void* d_ws, size_t ws_size,
                              hipStream_t stream) {
    const float* x  = (const float*)d_in[0];
    const float* W1 = (const float*)d_in[1];
    const float* b1 = (const float*)d_in[2];
    const float* W2 = (const float*)d_in[3];
    const float* b2 = (const float*)d_in[4];
    const float* Wl = (const float*)d_in[5];
    const float* bl = (const float*)d_in[6];
    float* out = (float*)d_out;
    const int N = in_sizes[0] / 784;  // 8192
    fused_pipeline<<<N, TPB, 0, stream>>>(x, W1, b1, W2, b2, Wl, bl, out);
}